// Round 22
// baseline (430.330 us; speedup 1.0000x reference)
//
#include <hip/hip_runtime.h>
#include <hip/hip_bf16.h>
#include <math.h>

typedef __bf16 bf16;
typedef bf16  bf16x4 __attribute__((ext_vector_type(4)));
typedef bf16  bf16x8 __attribute__((ext_vector_type(8)));
typedef float f32x4  __attribute__((ext_vector_type(4)));

#define CD 192
#define NHEADS 6
#define LDA 204   // 408B = 102 dwords = 6 mod 32 -> fragment rows spread over 16 banks (~4-way)

// One fragment convention for BOTH A and B operands of mfma_f32_16x16x32_bf16:
// lane l supplies (row/col) = r0 + (l&15), k = k0 + 8*(l>>4) + j  (8 contiguous bf16 = 16B).
__device__ __forceinline__ bf16x8 ld_frag(const bf16* p, int r0, int k0, int ld) {
  const int l = threadIdx.x & 63;
  return *reinterpret_cast<const bf16x8*>(p + (r0 + (l & 15)) * ld + (k0 + 8 * (l >> 4)));
}

// Same fragment via two b64 reads (8B-aligned; LDA=204 rows are not 16B-aligned so the
// compiler cannot re-fuse into a b128). Temporaries die into the consuming MFMA.
__device__ __forceinline__ bf16x8 ld_frag2(const bf16* p, int r0, int k0, int ld) {
  const int l = threadIdx.x & 63;
  const bf16* a = p + (r0 + (l & 15)) * ld + (k0 + 8 * (l >> 4));
  bf16x4 lo = *reinterpret_cast<const bf16x4*>(a);
  bf16x4 hi = *reinterpret_cast<const bf16x4*>(a + 4);
  bf16x8 r;
  r[0] = lo[0]; r[1] = lo[1]; r[2] = lo[2]; r[3] = lo[3];
  r[4] = hi[0]; r[5] = hi[1]; r[6] = hi[2]; r[7] = hi[3];
  return r;
}

__device__ __forceinline__ f32x4 mfma16(bf16x8 a, bf16x8 b, f32x4 c) {
  return __builtin_amdgcn_mfma_f32_16x16x32_bf16(a, b, c, 0, 0, 0);
}

// tanh-approx GELU with rcp instead of divide: max abs err ~1e-3.
__device__ __forceinline__ float gelu_f(float v) {
  const float e = __expf(-1.5957691216057308f * (v + 0.044715f * v * v * v));
  return v * __builtin_amdgcn_rcpf(1.f + e);
}

// ---------------- weight pack: fragment-major layout --------------------------------------
__global__ void prep_pack(const float* __restrict__ src, bf16* __restrict__ dst, int K, int N) {
  const int t = blockIdx.x * 256 + threadIdx.x;
  const int ktiles = K >> 5;
  const int total = (N >> 4) * ktiles * 64;
  if (t >= total) return;
  const int l  = t & 63;
  const int r  = t >> 6;
  const int kt = r % ktiles;
  const int ng = r / ktiles;
  const int n  = ng * 16 + (l & 15);
  const int k0 = kt * 32 + 8 * (l >> 4);
  bf16x8 v;
  #pragma unroll
  for (int j = 0; j < 8; ++j) v[j] = (bf16)src[(size_t)(k0 + j) * N + n];
  *(reinterpret_cast<bf16x8*>(dst) + t) = v;
}

// ---------------- fused rel-bias + shift-mask table: bm[4][6][64][64] fp32 ----------------
__global__ void prep_bm(const float* __restrict__ relb, float* __restrict__ bm) {
  const int idx = blockIdx.x * 256 + threadIdx.x;
  if (idx >= 4 * 6 * 64 * 64) return;
  const int k = idx & 63;
  const int r = (idx >> 6) & 63;
  const int h = (idx >> 12) % 6;
  const int c = idx / (4096 * 6);
  float v = -3000.f;
  if (r < 49 && k < 49) {
    const int rh = r / 7, rw = r % 7, kh = k / 7, kw = k % 7;
    const int crh = (c & 2) ? (rh < 4 ? 1 : 2) : 0;
    const int crw = (c & 1) ? (rw < 4 ? 1 : 2) : 0;
    const int ckh = (c & 2) ? (kh < 4 ? 1 : 2) : 0;
    const int ckw = (c & 1) ? (kw < 4 ? 1 : 2) : 0;
    const float mask = (crh == ckh && crw == ckw) ? 0.f : -100.f;
    v = relb[((rh - kh + 6) * 13 + (rw - kw + 6)) * 6 + h] + mask;
  }
  bm[idx] = v;
}

// ---------------- attention v20: R19 + ISOLATED LDA=204 de-conflicted big tiles ------------
// 1 blk/CU, 12 waves, 5 barriers, deduped GEMM maps, reg-residual, QKV-B prefetch under LN.
// No proj-B prefetch (R20's spill source). Only sA/sAO/sPO tiles move to stride 204 + b64 reads.
__global__ __launch_bounds__(768, 1)
void swin_attn_kernel(const float* __restrict__ x,
                      const float* __restrict__ n1w, const float* __restrict__ n1b,
                      const bf16* __restrict__ wqf, const float* __restrict__ qkvb,
                      const bf16* __restrict__ wpf, const float* __restrict__ projb,
                      const float* __restrict__ bm,
                      float* __restrict__ out)
{
  __shared__ alignas(16) bf16 sQ[NHEADS][64 * 40];   // [head][row][chan 0..31] pad 40
  __shared__ alignas(16) bf16 sK[NHEADS][64 * 40];
  __shared__ alignas(16) bf16 sVT[NHEADS][32 * 72];  // [head][chan][key] pad 72 -> sPO overlay
  __shared__ alignas(16) bf16 sU[NHEADS * 64 * 72];  // sA -> sP -> attnout (sA/sAO use LDA)

  const int l    = threadIdx.x & 63;
  const int wv   = threadIdx.x >> 6;     // 0..11
  const int h    = wv >> 1;              // head (scores/softmax/PV phases)
  const int half = wv & 1;               // row-half
  const int r0w  = half * 32;
  const int b  = blockIdx.x >> 6;
  const int wi = blockIdx.x & 63;
  const int wh = wi >> 3, ww = wi & 7;
  const int cw = ((wh == 7) ? 2 : 0) + ((ww == 7) ? 1 : 0);

  bf16* sA = sU;   // [64][LDA]

  // ---- x gather (phase 1) + QKV-B prefetch: both issued before LN compute ----
  float xv0[5], xv1[5], xv2[5];
  size_t basea[5];
  #pragma unroll
  for (int it = 0; it < 5; ++it) {
    const int t = wv + it * 12;
    if (t < 49) {
      const int th = t / 7, tw = t - 7 * th;
      const int ho = (wh * 7 + th + 3) % 56;     // roll(-3) folded into gather
      const int wo = (ww * 7 + tw + 3) % 56;
      const size_t base = ((size_t)b * 3136 + ho * 56 + wo) * CD;
      basea[it] = base;
      xv0[it] = x[base + l]; xv1[it] = x[base + l + 64]; xv2[it] = x[base + l + 128];
    }
  }
  // QKV B-fragments for this wave's 48-col slice (latency hides under LN + B1)
  const bf16x8* bq = reinterpret_cast<const bf16x8*>(wqf) + l;
  bf16x8 bqr[3][6];
  #pragma unroll
  for (int nt = 0; nt < 3; ++nt)
    #pragma unroll
    for (int ks = 0; ks < 6; ++ks)
      bqr[nt][ks] = bq[((wv * 3 + nt) * 6 + ks) * 64];

  // ---- LN1 compute -> sA ----
  {
    const float w0 = n1w[l], w1 = n1w[l + 64], w2 = n1w[l + 128];
    const float c0 = n1b[l], c1 = n1b[l + 64], c2 = n1b[l + 128];
    #pragma unroll
    for (int it = 0; it < 5; ++it) {
      const int t = wv + it * 12;
      if (t < 49) {
        const float v0 = xv0[it], v1 = xv1[it], v2 = xv2[it];
        float s  = v0 + v1 + v2;
        float ss = v0 * v0 + v1 * v1 + v2 * v2;
        #pragma unroll
        for (int off = 32; off; off >>= 1) { s += __shfl_xor(s, off); ss += __shfl_xor(ss, off); }
        const float mean = s * (1.f / 192.f);
        const float inv  = rsqrtf(ss * (1.f / 192.f) - mean * mean + 1e-5f);
        sA[t * LDA + l]       = (bf16)((v0 - mean) * inv * w0 + c0);
        sA[t * LDA + l + 64]  = (bf16)((v1 - mean) * inv * w1 + c1);
        sA[t * LDA + l + 128] = (bf16)((v2 - mean) * inv * w2 + c2);
      }
    }
    for (int i = threadIdx.x; i < 15 * LDA; i += 768) sA[49 * LDA + i] = (bf16)0.f;
  }
  __syncthreads();   // B1: sA ready

  // ---- bm prefetch: 32 values/lane (for softmax phase; latency hides under QKV MFMAs) ----
  float bmreg[2][4][4];
  {
    const float* bmb = bm + ((size_t)(cw * 6 + h) << 12) + (l & 15);
    #pragma unroll
    for (int mt = 0; mt < 2; ++mt)
      #pragma unroll
      for (int i = 0; i < 4; ++i) {
        const int r = r0w + mt * 16 + (l >> 4) * 4 + i;
        #pragma unroll
        for (int nt = 0; nt < 4; ++nt)
          bmreg[mt][i][nt] = bmb[r * 64 + nt * 16];
      }
  }

  // ---- QKV GEMM (col-sliced): wave = cols [wv*48, +48) x ALL 64 rows; B already in regs ---
  {
    const int cs = wv;
    f32x4 acc[3][4] = {};
    #pragma unroll
    for (int ks = 0; ks < 6; ++ks) {
      const int k0 = ks * 32;
      bf16x8 af[4];
      #pragma unroll
      for (int mt = 0; mt < 4; ++mt) af[mt] = ld_frag2(sA, mt * 16, k0, LDA);
      #pragma unroll
      for (int nt = 0; nt < 3; ++nt) {
        #pragma unroll
        for (int mt = 0; mt < 4; ++mt) acc[nt][mt] = mfma16(af[mt], bqr[nt][ks], acc[nt][mt]);
      }
    }
    #pragma unroll
    for (int nt = 0; nt < 3; ++nt) {
      const int col0 = cs * 48 + nt * 16;        // global qkv column base (0..560)
      const int which = col0 / 192;              // 0=q 1=k 2=v
      const int rem   = col0 - which * 192;
      const int hh    = rem >> 5;                // head
      const int cc    = (rem & 31) + (l & 15);   // channel within head
      const float bias = qkvb[col0 + (l & 15)];
      #pragma unroll
      for (int mt = 0; mt < 4; ++mt) {
        const int rb = mt * 16 + (l >> 4) * 4;
        if (which == 2) {
          bf16x4 pv;
          #pragma unroll
          for (int i = 0; i < 4; ++i) pv[i] = (bf16)(acc[nt][mt][i] + bias);
          *reinterpret_cast<bf16x4*>(&sVT[hh][cc * 72 + rb]) = pv;   // 144cc+2rb: 8B aligned
        } else if (which == 0) {
          #pragma unroll
          for (int i = 0; i < 4; ++i)
            sQ[hh][(rb + i) * 40 + cc] = (bf16)((acc[nt][mt][i] + bias) * 0.17677669529663689f);
        } else {
          #pragma unroll
          for (int i = 0; i < 4; ++i)
            sK[hh][(rb + i) * 40 + cc] = (bf16)(acc[nt][mt][i] + bias);
        }
      }
    }
  }
  __syncthreads();   // B2: QKV ready; sA dead -> sP region may be written

  // ---- scores + bm + softmax (wave = head x half; no-max, rcp) ----
  bf16* sP = sU + h * (64 * 72);
  {
    f32x4 sc[2][4] = {};
    bf16x8 qf0 = ld_frag(sQ[h], r0w,      0, 40);
    bf16x8 qf1 = ld_frag(sQ[h], r0w + 16, 0, 40);
    #pragma unroll
    for (int nt = 0; nt < 4; ++nt) {
      const bf16x8 kf = ld_frag(sK[h], nt * 16, 0, 40);
      sc[0][nt] = mfma16(qf0, kf, sc[0][nt]);
      sc[1][nt] = mfma16(qf1, kf, sc[1][nt]);
    }
    #pragma unroll
    for (int mt = 0; mt < 2; ++mt)
      #pragma unroll
      for (int i = 0; i < 4; ++i) {
        const int r = r0w + mt * 16 + (l >> 4) * 4 + i;
        float p[4], sum = 0.f;
        #pragma unroll
        for (int nt = 0; nt < 4; ++nt) {
          p[nt] = __expf(sc[mt][nt][i] + bmreg[mt][i][nt]);   // masked: exp(-100)->0
          sum += p[nt];
        }
        #pragma unroll
        for (int off = 1; off < 16; off <<= 1) sum += __shfl_xor(sum, off);
        const float isum = __builtin_amdgcn_rcpf(sum);
        #pragma unroll
        for (int nt = 0; nt < 4; ++nt)
          sP[r * 72 + nt * 16 + (l & 15)] = (bf16)(p[nt] * isum);
      }
  }

  // ---- PV: rows [r0w, +32), output channels of head h ----
  f32x4 o[2][2] = {};
  #pragma unroll
  for (int ks = 0; ks < 2; ++ks) {
    const int k0 = ks * 32;
    bf16x8 pf0 = ld_frag(sP, r0w,      k0, 72);
    bf16x8 pf1 = ld_frag(sP, r0w + 16, k0, 72);
    #pragma unroll
    for (int nt = 0; nt < 2; ++nt) {
      const bf16x8 vf = ld_frag(sVT[h], nt * 16, k0, 72);
      o[0][nt] = mfma16(pf0, vf, o[0][nt]);
      o[1][nt] = mfma16(pf1, vf, o[1][nt]);
    }
  }
  __syncthreads();   // B3: all sP reads AND all sVT reads done
  {
    bf16* sAO = sU;  // [64][LDA]
    #pragma unroll
    for (int nt = 0; nt < 2; ++nt) {
      const int c = h * 32 + nt * 16 + (l & 15);
      #pragma unroll
      for (int mt = 0; mt < 2; ++mt)
        #pragma unroll
        for (int i = 0; i < 4; ++i) {
          const int r = r0w + mt * 16 + (l >> 4) * 4 + i;
          sAO[r * LDA + c] = (bf16)o[mt][nt][i];
        }
    }
  }
  __syncthreads();   // B4: attnout ready

  // ---- proj (n-tile-sliced): wave = cols [wv*16,+16) x ALL 64 rows; B loaded in-loop ----
  // sPO staged into the DEAD sVT region -> no barrier needed between proj and staging.
  f32x4 po[4] = {};
  {
    const bf16* sAO = sU;
    const bf16x8* bp = reinterpret_cast<const bf16x8*>(wpf) + l;
    #pragma unroll
    for (int ks = 0; ks < 6; ++ks) {
      const int k0 = ks * 32;
      const bf16x8 bfr = bp[(wv * 6 + ks) * 64];
      #pragma unroll
      for (int mt = 0; mt < 4; ++mt) {
        bf16x8 af = ld_frag2(sAO, mt * 16, k0, LDA);
        po[mt] = mfma16(af, bfr, po[mt]);
      }
    }
  }
  {
    bf16* sPO = &sVT[0][0];  // [64][LDA] overlay (13056 <= 13824 elems)
    const int c = wv * 16 + (l & 15);
    const float bias = projb[c];
    #pragma unroll
    for (int mt = 0; mt < 4; ++mt)
      #pragma unroll
      for (int i = 0; i < 4; ++i) {
        const int r = mt * 16 + (l >> 4) * 4 + i;
        sPO[r * LDA + c] = (bf16)(po[mt][i] + bias);
      }
  }
  __syncthreads();   // B5: sPO ready

  // ---- writeout: residual from REGISTERS (x read once), contiguous rows ----
  {
    const bf16* sPO = &sVT[0][0];
    #pragma unroll
    for (int it = 0; it < 5; ++it) {
      const int r = wv + it * 12;
      if (r < 49) {
        const size_t base = basea[it];
        out[base + l]       = (float)sPO[r * LDA + l]       + xv0[it];
        out[base + l + 64]  = (float)sPO[r * LDA + l + 64]  + xv1[it];
        out[base + l + 128] = (float)sPO[r * LDA + l + 128] + xv2[it];
      }
    }
  }
}

// ---------------- MLP v4.1 (R13-proven): FC2-B prefetch only, chunk-64 dbuf, 3 blocks/CU ---
__global__ __launch_bounds__(512, 6)
void swin_mlp_kernel(const float* __restrict__ n2w, const float* __restrict__ n2b,
                     const bf16* __restrict__ w1f, const float* __restrict__ fb1,
                     const bf16* __restrict__ w2f, const float* __restrict__ fb2,
                     float* __restrict__ io)
{
  __shared__ alignas(16) bf16 sA[64 * 200];     // 25.6KB
  __shared__ alignas(16) bf16 sH[2][64 * 72];   // 18.4KB hidden chunk dbuf [64][64]
  const int l  = threadIdx.x & 63;
  const int wv = threadIdx.x >> 6;   // 0..7
  const int wr = wv & 1;             // M-half
  const int wc = wv >> 1;            // N-quarter
  const size_t t0 = (size_t)blockIdx.x * 64;

  // ---- LN2 ----
  {
    const float w0 = n2w[l], w1 = n2w[l + 64], w2 = n2w[l + 128];
    const float c0 = n2b[l], c1 = n2b[l + 64], c2 = n2b[l + 128];
    for (int t = wv; t < 64; t += 8) {
      const float* xr = io + (t0 + t) * CD;
      float v0 = xr[l], v1 = xr[l + 64], v2 = xr[l + 128];
      float s  = v0 + v1 + v2;
      float ss = v0 * v0 + v1 * v1 + v2 * v2;
      #pragma unroll
      for (int off = 32; off; off >>= 1) { s += __shfl_xor(s, off); ss += __shfl_xor(ss, off); }
      const float mean = s * (1.f / 192.f);
      const float inv  = rsqrtf(ss * (1.f / 192.f) - mean * mean + 1e-5f);
      sA[t * 200 + l]       = (bf16)((v0 - mean) * inv * w0 + c0);
      sA[t * 200 + l + 64]  = (bf16)((v1 - mean) * inv * w1 + c1);
      sA[t * 200 + l + 128] = (bf16)((v2 - mean) * inv * w2 + c2);
    }
  }
  __syncthreads();

  f32x4 oacc[2][3] = {};   // FC2 out: rows wr*32+mt*16, cols wc*48+nt*16 (persistent)
  const bf16x8* w1p = reinterpret_cast<const bf16x8*>(w1f) + l;
  const bf16x8* w2p = reinterpret_cast<const bf16x8*>(w2f) + l;

  for (int kc = 0; kc < 12; ++kc) {
    bf16* hb = sH[kc & 1];
    f32x4 acc[2] = {};
    // ---- FC1 chunk: cols kc*64 + wc*16, rows wr*32..+32 ----
    {
      bf16x8 b1[6];
      const bf16x8* b1p = w1p + ((kc * 4 + wc) * 6) * 64;
      #pragma unroll
      for (int ks = 0; ks < 6; ++ks) b1[ks] = b1p[ks * 64];

      #pragma unroll
      for (int ks = 0; ks < 6; ++ks) {
        const int k0 = ks * 32;
        bf16x8 af0 = ld_frag(sA, wr * 32,      k0, 200);
        bf16x8 af1 = ld_frag(sA, wr * 32 + 16, k0, 200);
        acc[0] = mfma16(af0, b1[ks], acc[0]);
        acc[1] = mfma16(af1, b1[ks], acc[1]);
      }
    }  // b1 dead here

    // ---- FC2 B prefetch: independent of hb; latency hides under GELU + barrier + ds_reads
    bf16x8 b2[6];
    #pragma unroll
    for (int ks = 0; ks < 2; ++ks)
      #pragma unroll
      for (int nt = 0; nt < 3; ++nt)
        b2[ks * 3 + nt] = w2p[((wc * 3 + nt) * 24 + kc * 2 + ks) * 64];

    // ---- GELU epilogue -> hb ----
    {
      const int col = wc * 16 + (l & 15);
      const float bias = fb1[kc * 64 + col];
      #pragma unroll
      for (int mt = 0; mt < 2; ++mt)
        #pragma unroll
        for (int i = 0; i < 4; ++i) {
          const int r = wr * 32 + mt * 16 + (l >> 4) * 4 + i;
          hb[r * 72 + col] = (bf16)gelu_f(acc[mt][i] + bias);
        }
    }
    __syncthreads();   // hb ready; single barrier per chunk (dbuf covers WAR)
    // ---- FC2 accumulate: k-tiles kc*2+ks (B already in regs) ----
    #pragma unroll
    for (int ks = 0; ks < 2; ++ks) {
      const int k0 = ks * 32;
      bf16x8 af0 = ld_frag(hb, wr * 32,      k0, 72);
      bf16x8 af1 = ld_frag(hb, wr * 32 + 16, k0, 72);
      #pragma unroll
      for (int nt = 0; nt < 3; ++nt) {
        oacc[0][nt] = mfma16(af0, b2[ks * 3 + nt], oacc[0][nt]);
        oacc[1][nt] = mfma16(af1, b2[ks * 3 + nt], oacc[1][nt]);
      }
    }
  }

  // ---- epilogue: bias + residual, in-place; store non-temporal (never re-read) ----
  #pragma unroll
  for (int nt = 0; nt < 3; ++nt) {
    const int col = wc * 48 + nt * 16 + (l & 15);
    const float bias = fb2[col];
    #pragma unroll
    for (int mt = 0; mt < 2; ++mt)
      #pragma unroll
      for (int i = 0; i < 4; ++i) {
        const int r = wr * 32 + mt * 16 + (l >> 4) * 4 + i;
        const size_t idx = (t0 + r) * CD + col;
        __builtin_nontemporal_store(oacc[mt][nt][i] + bias + io[idx], &io[idx]);
      }
  }
}

extern "C" void kernel_launch(void* const* d_in, const int* in_sizes, int n_in,
                              void* d_out, int out_size, void* d_ws, size_t ws_size,
                              hipStream_t stream) {
  const float* x     = (const float*)d_in[0];
  const float* n1w   = (const float*)d_in[1];
  const float* n1b   = (const float*)d_in[2];
  const float* qkvw  = (const float*)d_in[3];
  const float* qkvb  = (const float*)d_in[4];
  const float* projw = (const float*)d_in[5];
  const float* projb = (const float*)d_in[6];
  const float* relb  = (const float*)d_in[7];
  const float* n2w   = (const float*)d_in[8];
  const float* n2b   = (const float*)d_in[9];
  const float* f1w   = (const float*)d_in[10];
  const float* f1b   = (const float*)d_in[11];
  const float* f2w   = (const float*)d_in[12];
  const float* f2b   = (const float*)d_in[13];

  char* ws = (char*)d_ws;
  bf16*  wqf = (bf16*)(ws + 0);        // qkv packed: 221184 B
  bf16*  wpf = (bf16*)(ws + 221184);   // proj packed: 73728 B
  bf16*  w1f = (bf16*)(ws + 294912);   // fc1 packed: 294912 B
  bf16*  w2f = (bf16*)(ws + 589824);   // fc2 packed: 294912 B
  float* bm  = (float*)(ws + 884736);  // bias+mask table: 393216 B

  prep_pack<<<(36 * 6 * 64 + 255) / 256, 256, 0, stream>>>(qkvw, wqf, 192, 576);
  prep_pack<<<(12 * 6 * 64 + 255) / 256, 256, 0, stream>>>(projw, wpf, 192, 192);
  prep_pack<<<(48 * 6 * 64 + 255) / 256, 256, 0, stream>>>(f1w, w1f, 192, 768);
  prep_pack<<<(12 * 24 * 64 + 255) / 256, 256, 0, stream>>>(f2w, w2f, 768, 192);
  prep_bm<<<(4 * 6 * 64 * 64 + 255) / 256, 256, 0, stream>>>(relb, bm);

  swin_attn_kernel<<<4096, 768, 0, stream>>>(x, n1w, n1b, wqf, qkvb, wpf, projb, bm, (float*)d_out);
  swin_mlp_kernel<<<3136, 512, 0, stream>>>(n2w, n2b, w1f, f1b, w2f, f2b, (float*)d_out);
}

// Round 23
// 426.766 us; speedup vs baseline: 1.0084x; 1.0084x over previous
//
#include <hip/hip_runtime.h>
#include <hip/hip_bf16.h>
#include <math.h>

typedef __bf16 bf16;
typedef bf16  bf16x4 __attribute__((ext_vector_type(4)));
typedef bf16  bf16x8 __attribute__((ext_vector_type(8)));
typedef float f32x4  __attribute__((ext_vector_type(4)));

#define CD 192
#define NHEADS 6

// One fragment convention for BOTH A and B operands of mfma_f32_16x16x32_bf16:
// lane l supplies (row/col) = r0 + (l&15), k = k0 + 8*(l>>4) + j  (8 contiguous bf16 = 16B).
__device__ __forceinline__ bf16x8 ld_frag(const bf16* p, int r0, int k0, int ld) {
  const int l = threadIdx.x & 63;
  return *reinterpret_cast<const bf16x8*>(p + (r0 + (l & 15)) * ld + (k0 + 8 * (l >> 4)));
}

__device__ __forceinline__ f32x4 mfma16(bf16x8 a, bf16x8 b, f32x4 c) {
  return __builtin_amdgcn_mfma_f32_16x16x32_bf16(a, b, c, 0, 0, 0);
}

// tanh-approx GELU with rcp instead of divide: max abs err ~1e-3.
__device__ __forceinline__ float gelu_f(float v) {
  const float e = __expf(-1.5957691216057308f * (v + 0.044715f * v * v * v));
  return v * __builtin_amdgcn_rcpf(1.f + e);
}

// ---------------- weight pack: fragment-major layout --------------------------------------
__global__ void prep_pack(const float* __restrict__ src, bf16* __restrict__ dst, int K, int N) {
  const int t = blockIdx.x * 256 + threadIdx.x;
  const int ktiles = K >> 5;
  const int total = (N >> 4) * ktiles * 64;
  if (t >= total) return;
  const int l  = t & 63;
  const int r  = t >> 6;
  const int kt = r % ktiles;
  const int ng = r / ktiles;
  const int n  = ng * 16 + (l & 15);
  const int k0 = kt * 32 + 8 * (l >> 4);
  bf16x8 v;
  #pragma unroll
  for (int j = 0; j < 8; ++j) v[j] = (bf16)src[(size_t)(k0 + j) * N + n];
  *(reinterpret_cast<bf16x8*>(dst) + t) = v;
}

// ---------------- fused rel-bias + shift-mask table: bm[4][6][64][64] fp32 ----------------
__global__ void prep_bm(const float* __restrict__ relb, float* __restrict__ bm) {
  const int idx = blockIdx.x * 256 + threadIdx.x;
  if (idx >= 4 * 6 * 64 * 64) return;
  const int k = idx & 63;
  const int r = (idx >> 6) & 63;
  const int h = (idx >> 12) % 6;
  const int c = idx / (4096 * 6);
  float v = -3000.f;
  if (r < 49 && k < 49) {
    const int rh = r / 7, rw = r % 7, kh = k / 7, kw = k % 7;
    const int crh = (c & 2) ? (rh < 4 ? 1 : 2) : 0;
    const int crw = (c & 1) ? (rw < 4 ? 1 : 2) : 0;
    const int ckh = (c & 2) ? (kh < 4 ? 1 : 2) : 0;
    const int ckw = (c & 1) ? (kw < 4 ? 1 : 2) : 0;
    const float mask = (crh == ckh && crw == ckw) ? 0.f : -100.f;
    v = relb[((rh - kh + 6) * 13 + (rw - kw + 6)) * 6 + h] + mask;
  }
  bm[idx] = v;
}

// ---------------- attention v18 (session-best, 255us): 1 blk/CU, 12 waves, 5 barriers ------
// Deduped GEMM maps, reg-residual, QKV-B prefetch under LN (dies right after QKV -> no spill).
__global__ __launch_bounds__(768, 1)
void swin_attn_kernel(const float* __restrict__ x,
                      const float* __restrict__ n1w, const float* __restrict__ n1b,
                      const bf16* __restrict__ wqf, const float* __restrict__ qkvb,
                      const bf16* __restrict__ wpf, const float* __restrict__ projb,
                      const float* __restrict__ bm,
                      float* __restrict__ out)
{
  __shared__ alignas(16) bf16 sQ[NHEADS][64 * 40];   // [head][row][chan 0..31] pad 40
  __shared__ alignas(16) bf16 sK[NHEADS][64 * 40];
  __shared__ alignas(16) bf16 sVT[NHEADS][32 * 72];  // [head][chan][key] pad 72 -> sPO overlay
  __shared__ alignas(16) bf16 sU[NHEADS * 64 * 72];  // sA -> sP -> attnout

  const int l    = threadIdx.x & 63;
  const int wv   = threadIdx.x >> 6;     // 0..11
  const int h    = wv >> 1;              // head (scores/softmax/PV phases)
  const int half = wv & 1;               // row-half
  const int r0w  = half * 32;
  const int b  = blockIdx.x >> 6;
  const int wi = blockIdx.x & 63;
  const int wh = wi >> 3, ww = wi & 7;
  const int cw = ((wh == 7) ? 2 : 0) + ((ww == 7) ? 1 : 0);

  bf16* sA = sU;   // [64][200]

  // ---- x gather (phase 1) + QKV-B prefetch: both issued before LN compute ----
  float xv0[5], xv1[5], xv2[5];
  size_t basea[5];
  #pragma unroll
  for (int it = 0; it < 5; ++it) {
    const int t = wv + it * 12;
    if (t < 49) {
      const int th = t / 7, tw = t - 7 * th;
      const int ho = (wh * 7 + th + 3) % 56;     // roll(-3) folded into gather
      const int wo = (ww * 7 + tw + 3) % 56;
      const size_t base = ((size_t)b * 3136 + ho * 56 + wo) * CD;
      basea[it] = base;
      xv0[it] = x[base + l]; xv1[it] = x[base + l + 64]; xv2[it] = x[base + l + 128];
    }
  }
  // QKV B-fragments for this wave's 48-col slice (latency hides under LN + B1)
  const bf16x8* bq = reinterpret_cast<const bf16x8*>(wqf) + l;
  bf16x8 bqr[3][6];
  #pragma unroll
  for (int nt = 0; nt < 3; ++nt)
    #pragma unroll
    for (int ks = 0; ks < 6; ++ks)
      bqr[nt][ks] = bq[((wv * 3 + nt) * 6 + ks) * 64];

  // ---- LN1 compute -> sA ----
  {
    const float w0 = n1w[l], w1 = n1w[l + 64], w2 = n1w[l + 128];
    const float c0 = n1b[l], c1 = n1b[l + 64], c2 = n1b[l + 128];
    #pragma unroll
    for (int it = 0; it < 5; ++it) {
      const int t = wv + it * 12;
      if (t < 49) {
        const float v0 = xv0[it], v1 = xv1[it], v2 = xv2[it];
        float s  = v0 + v1 + v2;
        float ss = v0 * v0 + v1 * v1 + v2 * v2;
        #pragma unroll
        for (int off = 32; off; off >>= 1) { s += __shfl_xor(s, off); ss += __shfl_xor(ss, off); }
        const float mean = s * (1.f / 192.f);
        const float inv  = rsqrtf(ss * (1.f / 192.f) - mean * mean + 1e-5f);
        sA[t * 200 + l]       = (bf16)((v0 - mean) * inv * w0 + c0);
        sA[t * 200 + l + 64]  = (bf16)((v1 - mean) * inv * w1 + c1);
        sA[t * 200 + l + 128] = (bf16)((v2 - mean) * inv * w2 + c2);
      }
    }
    for (int i = threadIdx.x; i < 15 * 200; i += 768) sA[49 * 200 + i] = (bf16)0.f;
  }
  __syncthreads();   // B1: sA ready

  // ---- bm prefetch: 32 values/lane (for softmax phase; latency hides under QKV MFMAs) ----
  float bmreg[2][4][4];
  {
    const float* bmb = bm + ((size_t)(cw * 6 + h) << 12) + (l & 15);
    #pragma unroll
    for (int mt = 0; mt < 2; ++mt)
      #pragma unroll
      for (int i = 0; i < 4; ++i) {
        const int r = r0w + mt * 16 + (l >> 4) * 4 + i;
        #pragma unroll
        for (int nt = 0; nt < 4; ++nt)
          bmreg[mt][i][nt] = bmb[r * 64 + nt * 16];
      }
  }

  // ---- QKV GEMM (col-sliced): wave = cols [wv*48, +48) x ALL 64 rows; B already in regs ---
  {
    const int cs = wv;
    f32x4 acc[3][4] = {};
    #pragma unroll
    for (int ks = 0; ks < 6; ++ks) {
      const int k0 = ks * 32;
      bf16x8 af[4];
      #pragma unroll
      for (int mt = 0; mt < 4; ++mt) af[mt] = ld_frag(sA, mt * 16, k0, 200);
      #pragma unroll
      for (int nt = 0; nt < 3; ++nt) {
        #pragma unroll
        for (int mt = 0; mt < 4; ++mt) acc[nt][mt] = mfma16(af[mt], bqr[nt][ks], acc[nt][mt]);
      }
    }
    #pragma unroll
    for (int nt = 0; nt < 3; ++nt) {
      const int col0 = cs * 48 + nt * 16;        // global qkv column base (0..560)
      const int which = col0 / 192;              // 0=q 1=k 2=v
      const int rem   = col0 - which * 192;
      const int hh    = rem >> 5;                // head
      const int cc    = (rem & 31) + (l & 15);   // channel within head
      const float bias = qkvb[col0 + (l & 15)];
      #pragma unroll
      for (int mt = 0; mt < 4; ++mt) {
        const int rb = mt * 16 + (l >> 4) * 4;
        if (which == 2) {
          bf16x4 pv;
          #pragma unroll
          for (int i = 0; i < 4; ++i) pv[i] = (bf16)(acc[nt][mt][i] + bias);
          *reinterpret_cast<bf16x4*>(&sVT[hh][cc * 72 + rb]) = pv;   // 144cc+2rb: 8B aligned
        } else if (which == 0) {
          #pragma unroll
          for (int i = 0; i < 4; ++i)
            sQ[hh][(rb + i) * 40 + cc] = (bf16)((acc[nt][mt][i] + bias) * 0.17677669529663689f);
        } else {
          #pragma unroll
          for (int i = 0; i < 4; ++i)
            sK[hh][(rb + i) * 40 + cc] = (bf16)(acc[nt][mt][i] + bias);
        }
      }
    }
  }
  __syncthreads();   // B2: QKV ready; sA dead -> sP region may be written

  // ---- scores + bm + softmax (wave = head x half; no-max, rcp) ----
  bf16* sP = sU + h * (64 * 72);
  {
    f32x4 sc[2][4] = {};
    bf16x8 qf0 = ld_frag(sQ[h], r0w,      0, 40);
    bf16x8 qf1 = ld_frag(sQ[h], r0w + 16, 0, 40);
    #pragma unroll
    for (int nt = 0; nt < 4; ++nt) {
      const bf16x8 kf = ld_frag(sK[h], nt * 16, 0, 40);
      sc[0][nt] = mfma16(qf0, kf, sc[0][nt]);
      sc[1][nt] = mfma16(qf1, kf, sc[1][nt]);
    }
    #pragma unroll
    for (int mt = 0; mt < 2; ++mt)
      #pragma unroll
      for (int i = 0; i < 4; ++i) {
        const int r = r0w + mt * 16 + (l >> 4) * 4 + i;
        float p[4], sum = 0.f;
        #pragma unroll
        for (int nt = 0; nt < 4; ++nt) {
          p[nt] = __expf(sc[mt][nt][i] + bmreg[mt][i][nt]);   // masked: exp(-100)->0
          sum += p[nt];
        }
        #pragma unroll
        for (int off = 1; off < 16; off <<= 1) sum += __shfl_xor(sum, off);
        const float isum = __builtin_amdgcn_rcpf(sum);
        #pragma unroll
        for (int nt = 0; nt < 4; ++nt)
          sP[r * 72 + nt * 16 + (l & 15)] = (bf16)(p[nt] * isum);
      }
  }

  // ---- PV: rows [r0w, +32), output channels of head h ----
  f32x4 o[2][2] = {};
  #pragma unroll
  for (int ks = 0; ks < 2; ++ks) {
    const int k0 = ks * 32;
    bf16x8 pf0 = ld_frag(sP, r0w,      k0, 72);
    bf16x8 pf1 = ld_frag(sP, r0w + 16, k0, 72);
    #pragma unroll
    for (int nt = 0; nt < 2; ++nt) {
      const bf16x8 vf = ld_frag(sVT[h], nt * 16, k0, 72);
      o[0][nt] = mfma16(pf0, vf, o[0][nt]);
      o[1][nt] = mfma16(pf1, vf, o[1][nt]);
    }
  }
  __syncthreads();   // B3: all sP reads AND all sVT reads done
  {
    bf16* sAO = sU;  // [64][200]
    #pragma unroll
    for (int nt = 0; nt < 2; ++nt) {
      const int c = h * 32 + nt * 16 + (l & 15);
      #pragma unroll
      for (int mt = 0; mt < 2; ++mt)
        #pragma unroll
        for (int i = 0; i < 4; ++i) {
          const int r = r0w + mt * 16 + (l >> 4) * 4 + i;
          sAO[r * 200 + c] = (bf16)o[mt][nt][i];
        }
    }
  }
  __syncthreads();   // B4: attnout ready

  // ---- proj (n-tile-sliced): wave = cols [wv*16,+16) x ALL 64 rows; no dup B-loads ----
  // sPO staged into the DEAD sVT region -> no barrier needed between proj and staging.
  f32x4 po[4] = {};
  {
    const bf16* sAO = sU;
    const bf16x8* bp = reinterpret_cast<const bf16x8*>(wpf) + l;
    #pragma unroll
    for (int ks = 0; ks < 6; ++ks) {
      const int k0 = ks * 32;
      const bf16x8 bfr = bp[(wv * 6 + ks) * 64];
      #pragma unroll
      for (int mt = 0; mt < 4; ++mt) {
        bf16x8 af = ld_frag(sAO, mt * 16, k0, 200);
        po[mt] = mfma16(af, bfr, po[mt]);
      }
    }
  }
  {
    bf16* sPO = &sVT[0][0];  // [64][200] overlay (13824 >= 12800 elems)
    const int c = wv * 16 + (l & 15);
    const float bias = projb[c];
    #pragma unroll
    for (int mt = 0; mt < 4; ++mt)
      #pragma unroll
      for (int i = 0; i < 4; ++i) {
        const int r = mt * 16 + (l >> 4) * 4 + i;
        sPO[r * 200 + c] = (bf16)(po[mt][i] + bias);
      }
  }
  __syncthreads();   // B5: sPO ready

  // ---- writeout: residual from REGISTERS (x read once), contiguous rows ----
  {
    const bf16* sPO = &sVT[0][0];
    #pragma unroll
    for (int it = 0; it < 5; ++it) {
      const int r = wv + it * 12;
      if (r < 49) {
        const size_t base = basea[it];
        out[base + l]       = (float)sPO[r * 200 + l]       + xv0[it];
        out[base + l + 64]  = (float)sPO[r * 200 + l + 64]  + xv1[it];
        out[base + l + 128] = (float)sPO[r * 200 + l + 128] + xv2[it];
      }
    }
  }
}

// ---------------- MLP v4.1 (R13-proven): FC2-B prefetch only, chunk-64 dbuf, 3 blocks/CU ---
__global__ __launch_bounds__(512, 6)
void swin_mlp_kernel(const float* __restrict__ n2w, const float* __restrict__ n2b,
                     const bf16* __restrict__ w1f, const float* __restrict__ fb1,
                     const bf16* __restrict__ w2f, const float* __restrict__ fb2,
                     float* __restrict__ io)
{
  __shared__ alignas(16) bf16 sA[64 * 200];     // 25.6KB
  __shared__ alignas(16) bf16 sH[2][64 * 72];   // 18.4KB hidden chunk dbuf [64][64]
  const int l  = threadIdx.x & 63;
  const int wv = threadIdx.x >> 6;   // 0..7
  const int wr = wv & 1;             // M-half
  const int wc = wv >> 1;            // N-quarter
  const size_t t0 = (size_t)blockIdx.x * 64;

  // ---- LN2 ----
  {
    const float w0 = n2w[l], w1 = n2w[l + 64], w2 = n2w[l + 128];
    const float c0 = n2b[l], c1 = n2b[l + 64], c2 = n2b[l + 128];
    for (int t = wv; t < 64; t += 8) {
      const float* xr = io + (t0 + t) * CD;
      float v0 = xr[l], v1 = xr[l + 64], v2 = xr[l + 128];
      float s  = v0 + v1 + v2;
      float ss = v0 * v0 + v1 * v1 + v2 * v2;
      #pragma unroll
      for (int off = 32; off; off >>= 1) { s += __shfl_xor(s, off); ss += __shfl_xor(ss, off); }
      const float mean = s * (1.f / 192.f);
      const float inv  = rsqrtf(ss * (1.f / 192.f) - mean * mean + 1e-5f);
      sA[t * 200 + l]       = (bf16)((v0 - mean) * inv * w0 + c0);
      sA[t * 200 + l + 64]  = (bf16)((v1 - mean) * inv * w1 + c1);
      sA[t * 200 + l + 128] = (bf16)((v2 - mean) * inv * w2 + c2);
    }
  }
  __syncthreads();

  f32x4 oacc[2][3] = {};   // FC2 out: rows wr*32+mt*16, cols wc*48+nt*16 (persistent)
  const bf16x8* w1p = reinterpret_cast<const bf16x8*>(w1f) + l;
  const bf16x8* w2p = reinterpret_cast<const bf16x8*>(w2f) + l;

  for (int kc = 0; kc < 12; ++kc) {
    bf16* hb = sH[kc & 1];
    f32x4 acc[2] = {};
    // ---- FC1 chunk: cols kc*64 + wc*16, rows wr*32..+32 ----
    {
      bf16x8 b1[6];
      const bf16x8* b1p = w1p + ((kc * 4 + wc) * 6) * 64;
      #pragma unroll
      for (int ks = 0; ks < 6; ++ks) b1[ks] = b1p[ks * 64];

      #pragma unroll
      for (int ks = 0; ks < 6; ++ks) {
        const int k0 = ks * 32;
        bf16x8 af0 = ld_frag(sA, wr * 32,      k0, 200);
        bf16x8 af1 = ld_frag(sA, wr * 32 + 16, k0, 200);
        acc[0] = mfma16(af0, b1[ks], acc[0]);
        acc[1] = mfma16(af1, b1[ks], acc[1]);
      }
    }  // b1 dead here

    // ---- FC2 B prefetch: independent of hb; latency hides under GELU + barrier + ds_reads
    bf16x8 b2[6];
    #pragma unroll
    for (int ks = 0; ks < 2; ++ks)
      #pragma unroll
      for (int nt = 0; nt < 3; ++nt)
        b2[ks * 3 + nt] = w2p[((wc * 3 + nt) * 24 + kc * 2 + ks) * 64];

    // ---- GELU epilogue -> hb ----
    {
      const int col = wc * 16 + (l & 15);
      const float bias = fb1[kc * 64 + col];
      #pragma unroll
      for (int mt = 0; mt < 2; ++mt)
        #pragma unroll
        for (int i = 0; i < 4; ++i) {
          const int r = wr * 32 + mt * 16 + (l >> 4) * 4 + i;
          hb[r * 72 + col] = (bf16)gelu_f(acc[mt][i] + bias);
        }
    }
    __syncthreads();   // hb ready; single barrier per chunk (dbuf covers WAR)
    // ---- FC2 accumulate: k-tiles kc*2+ks (B already in regs) ----
    #pragma unroll
    for (int ks = 0; ks < 2; ++ks) {
      const int k0 = ks * 32;
      bf16x8 af0 = ld_frag(hb, wr * 32,      k0, 72);
      bf16x8 af1 = ld_frag(hb, wr * 32 + 16, k0, 72);
      #pragma unroll
      for (int nt = 0; nt < 3; ++nt) {
        oacc[0][nt] = mfma16(af0, b2[ks * 3 + nt], oacc[0][nt]);
        oacc[1][nt] = mfma16(af1, b2[ks * 3 + nt], oacc[1][nt]);
      }
    }
  }

  // ---- epilogue: bias + residual, in-place; store non-temporal (never re-read) ----
  #pragma unroll
  for (int nt = 0; nt < 3; ++nt) {
    const int col = wc * 48 + nt * 16 + (l & 15);
    const float bias = fb2[col];
    #pragma unroll
    for (int mt = 0; mt < 2; ++mt)
      #pragma unroll
      for (int i = 0; i < 4; ++i) {
        const int r = wr * 32 + mt * 16 + (l >> 4) * 4 + i;
        const size_t idx = (t0 + r) * CD + col;
        __builtin_nontemporal_store(oacc[mt][nt][i] + bias + io[idx], &io[idx]);
      }
  }
}

extern "C" void kernel_launch(void* const* d_in, const int* in_sizes, int n_in,
                              void* d_out, int out_size, void* d_ws, size_t ws_size,
                              hipStream_t stream) {
  const float* x     = (const float*)d_in[0];
  const float* n1w   = (const float*)d_in[1];
  const float* n1b   = (const float*)d_in[2];
  const float* qkvw  = (const float*)d_in[3];
  const float* qkvb  = (const float*)d_in[4];
  const float* projw = (const float*)d_in[5];
  const float* projb = (const float*)d_in[6];
  const float* relb  = (const float*)d_in[7];
  const float* n2w   = (const float*)d_in[8];
  const float* n2b   = (const float*)d_in[9];
  const float* f1w   = (const float*)d_in[10];
  const float* f1b   = (const float*)d_in[11];
  const float* f2w   = (const float*)d_in[12];
  const float* f2b   = (const float*)d_in[13];

  char* ws = (char*)d_ws;
  bf16*  wqf = (bf16*)(ws + 0);        // qkv packed: 221184 B
  bf16*  wpf = (bf16*)(ws + 221184);   // proj packed: 73728 B
  bf16*  w1f = (bf16*)(ws + 294912);   // fc1 packed: 294912 B
  bf16*  w2f = (bf16*)(ws + 589824);   // fc2 packed: 294912 B
  float* bm  = (float*)(ws + 884736);  // bias+mask table: 393216 B

  prep_pack<<<(36 * 6 * 64 + 255) / 256, 256, 0, stream>>>(qkvw, wqf, 192, 576);
  prep_pack<<<(12 * 6 * 64 + 255) / 256, 256, 0, stream>>>(projw, wpf, 192, 192);
  prep_pack<<<(48 * 6 * 64 + 255) / 256, 256, 0, stream>>>(f1w, w1f, 192, 768);
  prep_pack<<<(12 * 24 * 64 + 255) / 256, 256, 0, stream>>>(f2w, w2f, 768, 192);
  prep_bm<<<(4 * 6 * 64 * 64 + 255) / 256, 256, 0, stream>>>(relb, bm);

  swin_attn_kernel<<<4096, 768, 0, stream>>>(x, n1w, n1b, wqf, qkvb, wpf, projb, bm, (float*)d_out);
  swin_mlp_kernel<<<3136, 512, 0, stream>>>(n2w, n2b, w1f, f1b, w2f, f2b, (float*)d_out);
}